// Round 10
// baseline (94.980 us; speedup 1.0000x reference)
//
#include <hip/hip_runtime.h>
#include <hip/hip_bf16.h>
#include <math.h>

// Problem constants (Mask2Former pixel decoder / MS-deformable attention)
#define BB 4
#define SEQ 5376
#define DD 256
#define NH 8
#define NL 3
#define NP 4
#define DH 32
#define MTOT (BB * SEQ)          // 21504 rows for all GEMMs

typedef __attribute__((ext_vector_type(8))) short bf16x8;
typedef __attribute__((ext_vector_type(4))) float f32x4;

__device__ __forceinline__ ushort f2b(float f) {
    __hip_bfloat16 h = __float2bfloat16(f);
    return *reinterpret_cast<ushort*>(&h);
}

// ---------------------------------------------------------------------------
// Fused prep: blocks [0,800] transpose weights -> Wt[800][256] bf16 (+bias
// combine at block 800); blocks [801, 801+2048) convert hidden -> bf16 and
// (hidden+pos) -> bf16 (grid-stride).
// ---------------------------------------------------------------------------
__global__ __launch_bounds__(256) void prep_all(
    const float* __restrict__ hidden, const float* __restrict__ pos,
    const float* __restrict__ Wv, const float* __restrict__ Wo,
    const float* __restrict__ Wa, const float* __restrict__ Wout,
    const float* __restrict__ bo, const float* __restrict__ ba,
    ushort4* __restrict__ hb, ushort4* __restrict__ hsb,
    ushort* __restrict__ Wt, float* __restrict__ bcomb, int n4) {
    int bid = blockIdx.x;
    int tid = threadIdx.x;
    if (bid <= 800) {
        if (bid == 800) {
            for (int i = tid; i < 288; i += 256)
                bcomb[i] = (i < 192) ? bo[i] : ba[i - 192];
            return;
        }
        int row = bid;
        const float* src;
        int N, n;
        if (row < 256)      { src = Wv;   N = 256; n = row; }
        else if (row < 448) { src = Wo;   N = 192; n = row - 256; }
        else if (row < 544) { src = Wa;   N = 96;  n = row - 448; }
        else                { src = Wout; N = 256; n = row - 544; }
        float v = src[(size_t)tid * N + n];
        Wt[(size_t)row * 256 + tid] = f2b(v);
        return;
    }
    // activation conversion
    const float4* h4 = (const float4*)hidden;
    const float4* p4 = (const float4*)pos;
    int i = (bid - 801) * 256 + tid;
    int stride = (gridDim.x - 801) * 256;
    for (; i < n4; i += stride) {
        float4 a = h4[i], b = p4[i];
        ushort4 ua, us;
        ua.x = f2b(a.x); ua.y = f2b(a.y); ua.z = f2b(a.z); ua.w = f2b(a.w);
        us.x = f2b(a.x + b.x); us.y = f2b(a.y + b.y);
        us.z = f2b(a.z + b.z); us.w = f2b(a.w + b.w);
        hb[i] = ua;
        hsb[i] = us;
    }
}

// ---------------------------------------------------------------------------
// bf16 MFMA GEMM: C[M,N] = A[M,K]@W[K,N] + bias  (A bf16 [M][K], Wt bf16 [N][K])
// BM=128, BN=128, BK=64. 256 threads = 4 waves 2x2; wave tile 64x64 via 4x4
// fragments of mfma_f32_16x16x32_bf16; 32 MFMA per wave per barrier pair.
// OBF: bf16 output, else fp32. N guarded.
// ---------------------------------------------------------------------------
template<bool OBF>
__global__ __launch_bounds__(256) void gemm_mfma(
    const ushort* __restrict__ A, const ushort* __restrict__ Wt,
    const float* __restrict__ bias, void* __restrict__ Cout,
    int M, int N, int K) {
    const int BM = 128, BN = 128, BK = 64, PK = 72;   // PK: padded LDS row
    __shared__ ushort As[BM][PK];
    __shared__ ushort Bs[BN][PK];
    int bm = blockIdx.y * BM;
    int bn = blockIdx.x * BN;
    int tid = threadIdx.x;
    int lane = tid & 63;
    int wid = tid >> 6;
    int wr = wid >> 1, wc = wid & 1;     // 2x2 wave grid
    int lr = lane & 15;                  // row-in-frag (A) / col (B,C)
    int kg = lane >> 4;                  // k-group 0..3

    f32x4 acc[4][4] = {};

    for (int k0 = 0; k0 < K; k0 += BK) {
        // stage A: 128 rows x 64 bf16 = 1024 chunks of 8 bf16 (16B)
        #pragma unroll
        for (int c = 0; c < 4; c++) {
            int e = tid + 256 * c;
            int row = e >> 3, q = e & 7;
            const ushort* src = A + (size_t)(bm + row) * K + k0 + 8 * q;
            *(bf16x8*)&As[row][8 * q] = *(const bf16x8*)src;
        }
        // stage B: 128 rows x 64 bf16 = 1024 chunks
        #pragma unroll
        for (int c = 0; c < 4; c++) {
            int e = tid + 256 * c;
            int row = e >> 3, q = e & 7;
            int gn = bn + row;
            bf16x8 v = {0, 0, 0, 0, 0, 0, 0, 0};
            if (gn < N) v = *(const bf16x8*)(Wt + (size_t)gn * K + k0 + 8 * q);
            *(bf16x8*)&Bs[row][8 * q] = v;
        }
        __syncthreads();
        #pragma unroll
        for (int ks = 0; ks < 2; ks++) {
            bf16x8 af[4], bfr[4];
            #pragma unroll
            for (int mf = 0; mf < 4; mf++)
                af[mf] = *(bf16x8*)&As[wr * 64 + mf * 16 + lr][ks * 32 + kg * 8];
            #pragma unroll
            for (int nf = 0; nf < 4; nf++)
                bfr[nf] = *(bf16x8*)&Bs[wc * 64 + nf * 16 + lr][ks * 32 + kg * 8];
            #pragma unroll
            for (int mf = 0; mf < 4; mf++)
                #pragma unroll
                for (int nf = 0; nf < 4; nf++)
                    acc[mf][nf] = __builtin_amdgcn_mfma_f32_16x16x32_bf16(
                        af[mf], bfr[nf], acc[mf][nf], 0, 0, 0);
        }
        __syncthreads();
    }

    // epilogue: C[row][col] = acc + bias[col]
    #pragma unroll
    for (int nf = 0; nf < 4; nf++) {
        int gc = bn + wc * 64 + nf * 16 + lr;
        if (gc >= N) continue;
        float bv = bias[gc];
        #pragma unroll
        for (int mf = 0; mf < 4; mf++) {
            int gr0 = bm + wr * 64 + mf * 16 + kg * 4;
            #pragma unroll
            for (int r = 0; r < 4; r++) {
                float v = acc[mf][nf][r] + bv;
                if constexpr (OBF)
                    ((ushort*)Cout)[(size_t)(gr0 + r) * N + gc] = f2b(v);
                else
                    ((float*)Cout)[(size_t)(gr0 + r) * N + gc] = v;
            }
        }
    }
}

// ---------------------------------------------------------------------------
// Deformable sampling v8: v7 structure at 64-thread blocks (2 queries).
// Phase 1: 256 slots = 2q x 8h x 16 lanes (lp<12 active); 16-lane shfl
//          softmax -> attn_out; tap idx/weights -> LDS. 4 passes of 64.
// Phase 2: lane = q*32 + lane5; h = lane5>>2, d8 = lane5&3 (8 ch, 16B loads).
// Smaller blocks: LDS 6.7KB no longer caps occupancy; barrier is wave-local.
// ---------------------------------------------------------------------------
struct Acc8 {
    float a0, a1, a2, a3, a4, a5, a6, a7;
};

__device__ __forceinline__ void fma8(Acc8& acc, float wt, uint4 u) {
    acc.a0 = fmaf(wt, __uint_as_float(u.x << 16), acc.a0);
    acc.a1 = fmaf(wt, __uint_as_float(u.x & 0xffff0000u), acc.a1);
    acc.a2 = fmaf(wt, __uint_as_float(u.y << 16), acc.a2);
    acc.a3 = fmaf(wt, __uint_as_float(u.y & 0xffff0000u), acc.a3);
    acc.a4 = fmaf(wt, __uint_as_float(u.z << 16), acc.a4);
    acc.a5 = fmaf(wt, __uint_as_float(u.z & 0xffff0000u), acc.a5);
    acc.a6 = fmaf(wt, __uint_as_float(u.w << 16), acc.a6);
    acc.a7 = fmaf(wt, __uint_as_float(u.w & 0xffff0000u), acc.a7);
}

__global__ __launch_bounds__(64) void msda_sample_v8(
    const ushort* __restrict__ value, const float* __restrict__ comb,
    const float* __restrict__ refp, float* __restrict__ attn_out,
    ushort* __restrict__ out) {
    __shared__ int4   s_idx[2][8][13];   // [q][h][lp], pad 12->13
    __shared__ float4 s_w[2][8][13];
    int tid = threadIdx.x;
    int bq0 = blockIdx.x * 2;

    // ---- phase 1: softmax + tap setup (256 slots, 4 passes of 64) ----
    #pragma unroll
    for (int it = 0; it < 4; it++) {
        int t = tid + it * 64;
        int lp = t & 15;
        int qh = t >> 4;                 // 0..15
        int q = qh >> 3, h = qh & 7;
        int bq = bq0 + q;
        bool active = lp < 12;
        const float* crow = comb + (size_t)bq * 288;
        float logit = active ? crow[192 + h * 12 + lp] : -INFINITY;
        float m = logit;
        m = fmaxf(m, __shfl_xor(m, 1, 16));
        m = fmaxf(m, __shfl_xor(m, 2, 16));
        m = fmaxf(m, __shfl_xor(m, 4, 16));
        m = fmaxf(m, __shfl_xor(m, 8, 16));
        float e = active ? expf(logit - m) : 0.f;
        float s = e;
        s += __shfl_xor(s, 1, 16);
        s += __shfl_xor(s, 2, 16);
        s += __shfl_xor(s, 4, 16);
        s += __shfl_xor(s, 8, 16);
        float aw = e / s;
        if (active) {
            attn_out[(size_t)bq * 96 + h * 12 + lp] = aw;
            int l = lp >> 2;
            int b = bq / SEQ;
            int Wl = 64 >> l;
            float fW = (float)Wl;
            float rx = refp[(size_t)bq * 6 + 2 * l];
            float ry = refp[(size_t)bq * 6 + 2 * l + 1];
            float ox = crow[h * 24 + lp * 2];
            float oy = crow[h * 24 + lp * 2 + 1];
            float x = rx * fW + ox - 0.5f;
            float y = ry * fW + oy - 0.5f;
            float x0f = floorf(x), y0f = floorf(y);
            float wx = x - x0f, wy = y - y0f;
            int x0 = (int)x0f, y0 = (int)y0f;
            int x1 = x0 + 1, y1 = y0 + 1;
            float vx0 = (x0 >= 0 && x0 < Wl) ? 1.f : 0.f;
            float vx1 = (x1 >= 0 && x1 < Wl) ? 1.f : 0.f;
            float vy0 = (y0 >= 0 && y0 < Wl) ? 1.f : 0.f;   // square levels
            float vy1 = (y1 >= 0 && y1 < Wl) ? 1.f : 0.f;
            int xc0 = min(max(x0, 0), Wl - 1);
            int xc1 = min(max(x1, 0), Wl - 1);
            int yc0 = min(max(y0, 0), Wl - 1);
            int yc1 = min(max(y1, 0), Wl - 1);
            int st = (l == 0) ? 0 : ((l == 1) ? 4096 : 5120);
            int rowbase = b * SEQ + st;
            s_idx[q][h][lp] = make_int4((rowbase + yc0 * Wl + xc0) << 8,
                                        (rowbase + yc0 * Wl + xc1) << 8,
                                        (rowbase + yc1 * Wl + xc0) << 8,
                                        (rowbase + yc1 * Wl + xc1) << 8);
            s_w[q][h][lp] = make_float4(aw * (1.f - wx) * (1.f - wy) * vx0 * vy0,
                                        aw * wx * (1.f - wy) * vx1 * vy0,
                                        aw * (1.f - wx) * wy * vx0 * vy1,
                                        aw * wx * wy * vx1 * vy1);
        }
    }
    __syncthreads();

    // ---- phase 2: gather + FMA; 8 channels (16B) per lane ----
    int q = tid >> 5;
    int lane5 = tid & 31;
    int h = lane5 >> 2, d8 = lane5 & 3;
    int bq = bq0 + q;
    int ch0 = h * 32 + d8 * 8;
    const ushort* vb = value + ch0;

    Acc8 acc = {0.f, 0.f, 0.f, 0.f, 0.f, 0.f, 0.f, 0.f};
    #pragma unroll
    for (int lp = 0; lp < 12; lp++) {
        int4 ii = s_idx[q][h][lp];
        float4 ww = s_w[q][h][lp];
        uint4 u0 = *(const uint4*)(vb + ii.x);
        uint4 u1 = *(const uint4*)(vb + ii.y);
        uint4 u2 = *(const uint4*)(vb + ii.z);
        uint4 u3 = *(const uint4*)(vb + ii.w);
        fma8(acc, ww.x, u0);
        fma8(acc, ww.y, u1);
        fma8(acc, ww.z, u2);
        fma8(acc, ww.w, u3);
    }

    bf16x8 o;
    o[0] = (short)f2b(acc.a0); o[1] = (short)f2b(acc.a1);
    o[2] = (short)f2b(acc.a2); o[3] = (short)f2b(acc.a3);
    o[4] = (short)f2b(acc.a4); o[5] = (short)f2b(acc.a5);
    o[6] = (short)f2b(acc.a6); o[7] = (short)f2b(acc.a7);
    *(bf16x8*)(out + (size_t)bq * 256 + ch0) = o;
}

// ---------------------------------------------------------------------------
extern "C" void kernel_launch(void* const* d_in, const int* in_sizes, int n_in,
                              void* d_out, int out_size, void* d_ws, size_t ws_size,
                              hipStream_t stream) {
    const float* hidden = (const float*)d_in[0];
    const float* pos    = (const float*)d_in[1];
    const float* refp   = (const float*)d_in[2];
    const float* Wv     = (const float*)d_in[3];
    const float* bv     = (const float*)d_in[4];
    const float* Wo     = (const float*)d_in[5];
    const float* bo     = (const float*)d_in[6];
    const float* Wa     = (const float*)d_in[7];
    const float* ba     = (const float*)d_in[8];
    const float* Wout   = (const float*)d_in[9];
    const float* bout   = (const float*)d_in[10];

    float* out      = (float*)d_out;                       // (B,SEQ,256)
    float* attn_out = out + (size_t)BB * SEQ * DD;         // (B,SEQ,NH,NL,NP)

    const size_t BSD = (size_t)BB * SEQ * DD;              // 5,505,024
    char* w = (char*)d_ws;
    ushort* value_bf = (ushort*)w;  w += BSD * 2;                 // bf16 value
    float*  comb     = (float*)w;   w += (size_t)MTOT * 288 * 4;  // off|logits
    ushort* sampb    = (ushort*)w;  w += BSD * 2;                 // bf16 sampled
    ushort* hb       = (ushort*)w;  w += BSD * 2;                 // bf16 hidden
    ushort* hsb      = (ushort*)w;  w += BSD * 2;                 // bf16 hidden+pos
    ushort* Wt       = (ushort*)w;  w += (size_t)800 * 256 * 2;   // bf16 weights^T
    float*  bcomb    = (float*)w;                                 // 288 bias

    // 1. fused prep: weights transpose + activation bf16 conversion
    {
        int n4 = (int)(BSD / 4);
        prep_all<<<801 + 2048, 256, 0, stream>>>(hidden, pos, Wv, Wo, Wa, Wout,
                                                 bo, ba, (ushort4*)hb, (ushort4*)hsb,
                                                 Wt, bcomb, n4);
    }

    const ushort* Wv_t    = Wt;
    const ushort* Wcomb_t = Wt + (size_t)256 * 256;   // rows: 192 Wo + 96 Wa
    const ushort* Wout_t  = Wt + (size_t)544 * 256;

    // 2. value = hidden @ Wv + bv  -> bf16
    {
        dim3 grid(DD / 128, MTOT / 128);
        gemm_mfma<true><<<grid, 256, 0, stream>>>(hb, Wv_t, bv, value_bf, MTOT, DD, DD);
    }
    // 3. comb = hs @ [Wo|Wa] + [bo|ba]  (N=288, fp32 out)
    {
        dim3 grid(3, MTOT / 128);
        gemm_mfma<false><<<grid, 256, 0, stream>>>(hsb, Wcomb_t, bcomb, comb, MTOT, 288, DD);
    }
    // 4. fused softmax + deformable sampling -> attn_out + sampled bf16
    {
        msda_sample_v8<<<MTOT / 2, 64, 0, stream>>>(value_bf, comb, refp,
                                                    attn_out, sampb);
    }
    // 5. out = sampled @ Wout + bout -> d_out
    {
        dim3 grid(DD / 128, MTOT / 128);
        gemm_mfma<false><<<grid, 256, 0, stream>>>(sampb, Wout_t, bout, out, MTOT, DD, DD);
    }
}